// Round 3
// baseline (334.355 us; speedup 1.0000x reference)
//
#include <hip/hip_runtime.h>
#include <cfloat>

static constexpr int kBS  = 512;
static constexpr int kL   = 68;
static constexpr int kIMG = 224;
static constexpr int kR2  = 49;
static constexpr int kLL  = kL * kL;            // 4624
static constexpr int kPairsTotal = kBS * kLL / 2;  // 1183744
static constexpr int kOutBlocks = kPairsTotal / 256; // 4624

// jnp.linspace(-3.5,3.5,7)[k]/224*2 — JAX convex-combination linspace,
// exact op order, no contraction. k=6: step=1.0 -> exactly 3.5.
__device__ __forceinline__ float lin_off(int k) {
  float step = __fdiv_rn((float)k, 6.0f);
  float a = __fmul_rn(-3.5f, __fsub_rn(1.0f, step));
  float b = __fmul_rn(3.5f, step);
  float x = __fadd_rn(a, b);
  return __fmul_rn(__fdiv_rn(x, 224.0f), 2.0f);
}

// K1 (R1-proven): one wave per (b,l) region; lanes 0..48 hold the 7x7 samples.
__global__ __launch_bounds__(256) void k_median(
    const float* __restrict__ depth, const float* __restrict__ lmk,
    const float* __restrict__ scale, const float* __restrict__ bbox,
    float* __restrict__ med, unsigned* __restrict__ ctl) {
  if (blockIdx.x == 0 && threadIdx.x == 0) ctl[0] = 0u;  // ticket for K3
  int wave = blockIdx.x * 4 + (threadIdx.x >> 6);
  int lane = threadIdx.x & 63;
  if (wave >= kBS * kL) return;
  int b = wave / kL;

  float lmx = lmk[wave * 2 + 0];
  float lmy = lmk[wave * 2 + 1];
  float sx = scale[b * 2 + 0], sy = scale[b * 2 + 1];
  float bx = bbox[b * 4 + 0],  by = bbox[b * 4 + 1];

  float tx = __fsub_rn(lmx, bx);
  tx = __fmul_rn(tx, sx); tx = __fdiv_rn(tx, 224.0f); tx = __fmul_rn(tx, 2.0f);
  float flmx = __fsub_rn(tx, 1.0f);
  float ty = __fsub_rn(lmy, by);
  ty = __fmul_rn(ty, sy); ty = __fdiv_rn(ty, 224.0f); ty = __fmul_rn(ty, 2.0f);
  float flmy = __fsub_rn(ty, 1.0f);

  float v = FLT_MAX;  // inactive lanes sort last; never selected
  if (lane < kR2) {
    int i = lane / 7, j = lane - i * 7;
    float gx = __fadd_rn(flmx, lin_off(j));
    float gy = __fadd_rn(flmy, lin_off(i));
    float ix = __fmul_rn(__fsub_rn(__fmul_rn(__fadd_rn(gx, 1.0f), 224.0f), 1.0f), 0.5f);
    float iy = __fmul_rn(__fsub_rn(__fmul_rn(__fadd_rn(gy, 1.0f), 224.0f), 1.0f), 0.5f);
    int xi = (int)rintf(ix), yi = (int)rintf(iy);
    bool valid = (xi >= 0) && (xi < kIMG) && (yi >= 0) && (yi < kIMG);
    int xc = min(max(xi, 0), kIMG - 1), yc = min(max(yi, 0), kIMG - 1);
    float dv = depth[(size_t)b * (kIMG * kIMG) + yc * kIMG + xc];
    v = valid ? dv : 0.0f;
  }

  int cnt = 0, rank = 0;
  for (int j = 0; j < kR2; ++j) {
    float vj = __shfl(v, j, 64);
    cnt += (vj <= 1e-4f) ? 1 : 0;
    rank += ((vj < v) || (vj == v && j < lane)) ? 1 : 0;
  }
  int st = min(max(cnt, 1), kR2 - 1);
  int k = (st + kR2 - 1) >> 1;
  unsigned long long sel = __ballot(lane < kR2 && rank == k);
  int src = __ffsll(sel) - 1;
  float m = __shfl(v, src, 64);
  if (lane == 0) med[wave] = m;
}

// K2: per-batch lower median of 68 medians; writes packed (median*500, mask).
__global__ __launch_bounds__(128) void k_mask(
    const float* __restrict__ med, float2* __restrict__ mf) {
  __shared__ float s[kL];
  __shared__ float mom_s;
  int b = blockIdx.x, t = threadIdx.x;
  if (t < kL) s[t] = med[b * kL + t];
  __syncthreads();
  if (t < kL) {
    float v = s[t];
    int rank = 0;
    for (int j = 0; j < kL; ++j) {
      float vj = s[j];
      rank += ((vj < v) || (vj == v && j < t)) ? 1 : 0;
    }
    if (rank == (kL - 1) / 2) mom_s = v;  // exactly one thread
  }
  __syncthreads();
  if (t < kL) {
    float v = s[t];
    float diff = fabsf(__fsub_rn(v, mom_s));
    float2 o;
    o.x = __fmul_rn(v, 500.0f);
    o.y = (diff < 0.18f) ? 1.0f : 0.0f;
    mf[b * kL + t] = o;
  }
}

// K3: 2 elements/thread over [512,68,68]; writes diff/mask, masked smooth-L1
// partials; last block (ticket) reduces 4624 contiguous double2 -> loss.
__global__ __launch_bounds__(256) void k_out(
    const float* __restrict__ rdp, const float2* __restrict__ mf,
    float* __restrict__ out_diff, float* __restrict__ out_mask,
    float* __restrict__ out0, unsigned* __restrict__ ctl,
    double* __restrict__ part) {
  __shared__ double sn[4], sd[4];
  __shared__ int lastFlag;
  int t = blockIdx.x * 256 + threadIdx.x;   // pair index
  int e = t * 2;
  unsigned b = (unsigned)e / (unsigned)kLL;
  int r = e - (int)b * kLL;
  unsigned i0 = (unsigned)r / (unsigned)kL;
  int j0 = r - (int)i0 * kL;
  unsigned i1 = (j0 == kL - 1) ? i0 + 1 : i0;
  int j1 = (j0 == kL - 1) ? 0 : j0 + 1;

  const float2* mfb = mf + b * kL;
  float2 a0 = mfb[i0], a1 = mfb[i1];
  float2 c0 = mfb[j0], c1 = mfb[j1];
  float2 rp = ((const float2*)rdp)[t];   // rdp base 8B-aligned, e even

  float diff0 = __fsub_rn(a0.x, c0.x);
  float diff1 = __fsub_rn(a1.x, c1.x);
  float mv0 = __fmul_rn(a0.y, c0.y);
  float mv1 = __fmul_rn(a1.y, c1.y);
  out_diff[e] = diff0; out_diff[e + 1] = diff1;
  out_mask[e] = mv0;   out_mask[e + 1] = mv1;

  float d0 = __fsub_rn(rp.x, diff0), d1 = __fsub_rn(rp.y, diff1);
  float ad0 = fabsf(d0), ad1 = fabsf(d1);
  float le0 = (ad0 < 1.0f) ? __fmul_rn(__fmul_rn(0.5f, d0), d0) : __fsub_rn(ad0, 0.5f);
  float le1 = (ad1 < 1.0f) ? __fmul_rn(__fmul_rn(0.5f, d1), d1) : __fsub_rn(ad1, 0.5f);
  double pn = (double)__fmul_rn(le0, mv0) + (double)__fmul_rn(le1, mv1);
  double pd = (double)mv0 + (double)mv1;

  for (int off = 32; off > 0; off >>= 1) {
    pn += __shfl_down(pn, off, 64);
    pd += __shfl_down(pd, off, 64);
  }
  int w = threadIdx.x >> 6;
  if ((threadIdx.x & 63) == 0) { sn[w] = pn; sd[w] = pd; }
  __syncthreads();
  if (threadIdx.x == 0) {
    double tn = sn[0] + sn[1] + sn[2] + sn[3];
    double td = sd[0] + sd[1] + sd[2] + sd[3];
    part[2 * blockIdx.x + 0] = tn;
    part[2 * blockIdx.x + 1] = td;
    __threadfence();
    unsigned old = atomicAdd(ctl, 1u);
    lastFlag = (old == (unsigned)(kOutBlocks - 1));
  }
  __syncthreads();
  if (lastFlag) {
    __threadfence();
    double n = 0.0, dd = 0.0;
    for (int i = threadIdx.x; i < kOutBlocks; i += 256) {
      n += part[2 * i + 0];
      dd += part[2 * i + 1];
    }
    for (int off = 32; off > 0; off >>= 1) {
      n += __shfl_down(n, off, 64);
      dd += __shfl_down(dd, off, 64);
    }
    if ((threadIdx.x & 63) == 0) { sn[threadIdx.x >> 6] = n; sd[threadIdx.x >> 6] = dd; }
    __syncthreads();
    if (threadIdx.x == 0) {
      double tn = sn[0] + sn[1] + sn[2] + sn[3];
      double td = sd[0] + sd[1] + sd[2] + sd[3];
      out0[0] = (float)(tn / (td + 1e-4));
    }
  }
}

extern "C" void kernel_launch(void* const* d_in, const int* in_sizes, int n_in,
                              void* d_out, int out_size, void* d_ws, size_t ws_size,
                              hipStream_t stream) {
  const float* rdp   = (const float*)d_in[0];  // [512,68,68]
  const float* depth = (const float*)d_in[1];  // [512,1,224,224]
  const float* lmk   = (const float*)d_in[2];  // [512,68,2]
  const float* scale = (const float*)d_in[3];  // [512,2]
  const float* bbox  = (const float*)d_in[4];  // [512,4]

  float* out = (float*)d_out;
  float* out_diff = out + 1;
  float* out_mask = out + 1 + (size_t)kBS * kLL;

  char* ws = (char*)d_ws;
  unsigned* ctl = (unsigned*)ws;                              // 128 B
  float*  med  = (float*)(ws + 128);                          // 139264 B
  float2* mf   = (float2*)(ws + 128 + 139264);                // 278528 B
  double* part = (double*)(ws + 128 + 139264 + 278528);       // 73984 B

  int nWaves = kBS * kL;          // 34816
  int nBlk1 = (nWaves + 3) / 4;   // 8704
  k_median<<<dim3(nBlk1), dim3(256), 0, stream>>>(depth, lmk, scale, bbox, med, ctl);
  k_mask<<<dim3(kBS), dim3(128), 0, stream>>>(med, mf);
  k_out<<<dim3(kOutBlocks), dim3(256), 0, stream>>>(rdp, mf, out_diff, out_mask,
                                                    out, ctl, part);
}

// Round 4
// 186.585 us; speedup vs baseline: 1.7920x; 1.7920x over previous
//
#include <hip/hip_runtime.h>
#include <cfloat>

static constexpr int kBS  = 512;
static constexpr int kL   = 68;
static constexpr int kIMG = 224;
static constexpr int kR2  = 49;
static constexpr int kLL  = kL * kL;                 // 4624
static constexpr int kPairsTotal = kBS * kLL / 2;    // 1183744
static constexpr int kOutBlocks = kPairsTotal / 256; // 4624

// jnp.linspace(-3.5,3.5,7)[k]/224*2 — JAX convex-combination linspace,
// exact op order, no contraction. k=6: step=1.0 -> exactly 3.5.
__device__ __forceinline__ float lin_off(int k) {
  float step = __fdiv_rn((float)k, 6.0f);
  float a = __fmul_rn(-3.5f, __fsub_rn(1.0f, step));
  float b = __fmul_rn(3.5f, step);
  float x = __fadd_rn(a, b);
  return __fmul_rn(__fdiv_rn(x, 224.0f), 2.0f);
}

// K1 (R1-proven): one wave per (b,l) region; lanes 0..48 hold the 7x7 samples.
__global__ __launch_bounds__(256) void k_median(
    const float* __restrict__ depth, const float* __restrict__ lmk,
    const float* __restrict__ scale, const float* __restrict__ bbox,
    float* __restrict__ med) {
  int wave = blockIdx.x * 4 + (threadIdx.x >> 6);
  int lane = threadIdx.x & 63;
  if (wave >= kBS * kL) return;
  int b = wave / kL;

  float lmx = lmk[wave * 2 + 0];
  float lmy = lmk[wave * 2 + 1];
  float sx = scale[b * 2 + 0], sy = scale[b * 2 + 1];
  float bx = bbox[b * 4 + 0],  by = bbox[b * 4 + 1];

  float tx = __fsub_rn(lmx, bx);
  tx = __fmul_rn(tx, sx); tx = __fdiv_rn(tx, 224.0f); tx = __fmul_rn(tx, 2.0f);
  float flmx = __fsub_rn(tx, 1.0f);
  float ty = __fsub_rn(lmy, by);
  ty = __fmul_rn(ty, sy); ty = __fdiv_rn(ty, 224.0f); ty = __fmul_rn(ty, 2.0f);
  float flmy = __fsub_rn(ty, 1.0f);

  float v = FLT_MAX;  // inactive lanes sort last; never selected
  if (lane < kR2) {
    int i = lane / 7, j = lane - i * 7;
    float gx = __fadd_rn(flmx, lin_off(j));
    float gy = __fadd_rn(flmy, lin_off(i));
    float ix = __fmul_rn(__fsub_rn(__fmul_rn(__fadd_rn(gx, 1.0f), 224.0f), 1.0f), 0.5f);
    float iy = __fmul_rn(__fsub_rn(__fmul_rn(__fadd_rn(gy, 1.0f), 224.0f), 1.0f), 0.5f);
    int xi = (int)rintf(ix), yi = (int)rintf(iy);
    bool valid = (xi >= 0) && (xi < kIMG) && (yi >= 0) && (yi < kIMG);
    int xc = min(max(xi, 0), kIMG - 1), yc = min(max(yi, 0), kIMG - 1);
    float dv = depth[(size_t)b * (kIMG * kIMG) + yc * kIMG + xc];
    v = valid ? dv : 0.0f;
  }

  int cnt = 0, rank = 0;
  for (int j = 0; j < kR2; ++j) {
    float vj = __shfl(v, j, 64);
    cnt += (vj <= 1e-4f) ? 1 : 0;
    rank += ((vj < v) || (vj == v && j < lane)) ? 1 : 0;
  }
  int st = min(max(cnt, 1), kR2 - 1);
  int k = (st + kR2 - 1) >> 1;
  unsigned long long sel = __ballot(lane < kR2 && rank == k);
  int src = __ffsll(sel) - 1;
  float m = __shfl(v, src, 64);
  if (lane == 0) med[wave] = m;
}

// K2: per-batch lower median of 68 medians; writes packed (median*500, mask).
__global__ __launch_bounds__(128) void k_mask(
    const float* __restrict__ med, float2* __restrict__ mf) {
  __shared__ float s[kL];
  __shared__ float mom_s;
  int b = blockIdx.x, t = threadIdx.x;
  if (t < kL) s[t] = med[b * kL + t];
  __syncthreads();
  if (t < kL) {
    float v = s[t];
    int rank = 0;
    for (int j = 0; j < kL; ++j) {
      float vj = s[j];
      rank += ((vj < v) || (vj == v && j < t)) ? 1 : 0;
    }
    if (rank == (kL - 1) / 2) mom_s = v;  // exactly one thread
  }
  __syncthreads();
  if (t < kL) {
    float v = s[t];
    float diff = fabsf(__fsub_rn(v, mom_s));
    float2 o;
    o.x = __fmul_rn(v, 500.0f);
    o.y = (diff < 0.18f) ? 1.0f : 0.0f;
    mf[b * kL + t] = o;
  }
}

// K3: 2 elements/thread over [512,68,68]; writes diff/mask + per-block
// masked smooth-L1 partials. NO fences/atomics (fence storm = R3 regression).
__global__ __launch_bounds__(256) void k_out(
    const float* __restrict__ rdp, const float2* __restrict__ mf,
    float* __restrict__ out_diff, float* __restrict__ out_mask,
    double* __restrict__ part) {
  __shared__ double sn[4], sd[4];
  int t = blockIdx.x * 256 + threadIdx.x;   // pair index
  int e = t * 2;
  unsigned b = (unsigned)e / (unsigned)kLL;
  int r = e - (int)b * kLL;
  unsigned i0 = (unsigned)r / (unsigned)kL;
  int j0 = r - (int)i0 * kL;
  unsigned i1 = (j0 == kL - 1) ? i0 + 1 : i0;
  int j1 = (j0 == kL - 1) ? 0 : j0 + 1;

  const float2* mfb = mf + b * kL;
  float2 a0 = mfb[i0], a1 = mfb[i1];
  float2 c0 = mfb[j0], c1 = mfb[j1];
  float2 rp = ((const float2*)rdp)[t];   // rdp base aligned, e even

  float diff0 = __fsub_rn(a0.x, c0.x);
  float diff1 = __fsub_rn(a1.x, c1.x);
  float mv0 = __fmul_rn(a0.y, c0.y);
  float mv1 = __fmul_rn(a1.y, c1.y);
  out_diff[e] = diff0; out_diff[e + 1] = diff1;
  out_mask[e] = mv0;   out_mask[e + 1] = mv1;

  float d0 = __fsub_rn(rp.x, diff0), d1 = __fsub_rn(rp.y, diff1);
  float ad0 = fabsf(d0), ad1 = fabsf(d1);
  float le0 = (ad0 < 1.0f) ? __fmul_rn(__fmul_rn(0.5f, d0), d0) : __fsub_rn(ad0, 0.5f);
  float le1 = (ad1 < 1.0f) ? __fmul_rn(__fmul_rn(0.5f, d1), d1) : __fsub_rn(ad1, 0.5f);
  double pn = (double)__fmul_rn(le0, mv0) + (double)__fmul_rn(le1, mv1);
  double pd = (double)mv0 + (double)mv1;

  for (int off = 32; off > 0; off >>= 1) {
    pn += __shfl_down(pn, off, 64);
    pd += __shfl_down(pd, off, 64);
  }
  int w = threadIdx.x >> 6;
  if ((threadIdx.x & 63) == 0) { sn[w] = pn; sd[w] = pd; }
  __syncthreads();
  if (threadIdx.x == 0) {
    part[2 * blockIdx.x + 0] = sn[0] + sn[1] + sn[2] + sn[3];
    part[2 * blockIdx.x + 1] = sd[0] + sd[1] + sd[2] + sd[3];
  }
}

__global__ __launch_bounds__(256) void k_final(
    const double* __restrict__ part, float* __restrict__ out0) {
  __shared__ double sn[4], sd[4];
  double pn = 0.0, pd = 0.0;
  for (int i = threadIdx.x; i < kOutBlocks; i += 256) {
    pn += part[2 * i + 0];
    pd += part[2 * i + 1];
  }
  for (int off = 32; off > 0; off >>= 1) {
    pn += __shfl_down(pn, off, 64);
    pd += __shfl_down(pd, off, 64);
  }
  int w = threadIdx.x >> 6;
  if ((threadIdx.x & 63) == 0) { sn[w] = pn; sd[w] = pd; }
  __syncthreads();
  if (threadIdx.x == 0) {
    double tn = sn[0] + sn[1] + sn[2] + sn[3];
    double td = sd[0] + sd[1] + sd[2] + sd[3];
    out0[0] = (float)(tn / (td + 1e-4));
  }
}

extern "C" void kernel_launch(void* const* d_in, const int* in_sizes, int n_in,
                              void* d_out, int out_size, void* d_ws, size_t ws_size,
                              hipStream_t stream) {
  const float* rdp   = (const float*)d_in[0];  // [512,68,68]
  const float* depth = (const float*)d_in[1];  // [512,1,224,224]
  const float* lmk   = (const float*)d_in[2];  // [512,68,2]
  const float* scale = (const float*)d_in[3];  // [512,2]
  const float* bbox  = (const float*)d_in[4];  // [512,4]

  float* out = (float*)d_out;
  float* out_diff = out + 1;
  float* out_mask = out + 1 + (size_t)kBS * kLL;

  char* ws = (char*)d_ws;
  float*  med  = (float*)(ws);                          // 139264 B
  float2* mf   = (float2*)(ws + 139264);                // 278528 B
  double* part = (double*)(ws + 139264 + 278528);       // 73984 B

  int nWaves = kBS * kL;          // 34816
  int nBlk1 = (nWaves + 3) / 4;   // 8704
  k_median<<<dim3(nBlk1), dim3(256), 0, stream>>>(depth, lmk, scale, bbox, med);
  k_mask<<<dim3(kBS), dim3(128), 0, stream>>>(med, mf);
  k_out<<<dim3(kOutBlocks), dim3(256), 0, stream>>>(rdp, mf, out_diff, out_mask, part);
  k_final<<<dim3(1), dim3(256), 0, stream>>>(part, out);
}

// Round 5
// 178.390 us; speedup vs baseline: 1.8743x; 1.0459x over previous
//
#include <hip/hip_runtime.h>
#include <cfloat>
#include <math.h>

static constexpr int kBS  = 512;
static constexpr int kL   = 68;
static constexpr int kIMG = 224;
static constexpr int kR2  = 49;
static constexpr int kLL  = kL * kL;                 // 4624
static constexpr int kPairsTotal = kBS * kLL / 2;    // 1183744
static constexpr int kOutBlocks = kPairsTotal / 256; // 4624

// jnp.linspace(-3.5,3.5,7)[k]/224*2 — JAX convex-combination linspace,
// exact op order, no contraction. k=6: step=1.0 -> exactly 3.5.
__device__ __forceinline__ float lin_off(int k) {
  float step = __fdiv_rn((float)k, 6.0f);
  float a = __fmul_rn(-3.5f, __fsub_rn(1.0f, step));
  float b = __fmul_rn(3.5f, step);
  float x = __fadd_rn(a, b);
  return __fmul_rn(__fdiv_rn(x, 224.0f), 2.0f);
}

// K1: one wave per (b,l) region; lanes 0..48 hold the 7x7 samples.
// Bitonic 64-lane sort (21 compare-exchange) + ballot count replaces the
// 49-iteration rank loop. Selected value identical: k-th order statistic.
__global__ __launch_bounds__(256) void k_median(
    const float* __restrict__ depth, const float* __restrict__ lmk,
    const float* __restrict__ scale, const float* __restrict__ bbox,
    float* __restrict__ med) {
  int wave = blockIdx.x * 4 + (threadIdx.x >> 6);
  int lane = threadIdx.x & 63;
  if (wave >= kBS * kL) return;
  int b = wave / kL;

  float lmx = lmk[wave * 2 + 0];
  float lmy = lmk[wave * 2 + 1];
  float sx = scale[b * 2 + 0], sy = scale[b * 2 + 1];
  float bx = bbox[b * 4 + 0],  by = bbox[b * 4 + 1];

  float tx = __fsub_rn(lmx, bx);
  tx = __fmul_rn(tx, sx); tx = __fdiv_rn(tx, 224.0f); tx = __fmul_rn(tx, 2.0f);
  float flmx = __fsub_rn(tx, 1.0f);
  float ty = __fsub_rn(lmy, by);
  ty = __fmul_rn(ty, sy); ty = __fdiv_rn(ty, 224.0f); ty = __fmul_rn(ty, 2.0f);
  float flmy = __fsub_rn(ty, 1.0f);

  float v = INFINITY;  // pad lanes sort last; never selected
  if (lane < kR2) {
    int i = lane / 7, j = lane - i * 7;
    float gx = __fadd_rn(flmx, lin_off(j));
    float gy = __fadd_rn(flmy, lin_off(i));
    float ix = __fmul_rn(__fsub_rn(__fmul_rn(__fadd_rn(gx, 1.0f), 224.0f), 1.0f), 0.5f);
    float iy = __fmul_rn(__fsub_rn(__fmul_rn(__fadd_rn(gy, 1.0f), 224.0f), 1.0f), 0.5f);
    int xi = (int)rintf(ix), yi = (int)rintf(iy);
    bool valid = (xi >= 0) && (xi < kIMG) && (yi >= 0) && (yi < kIMG);
    int xc = min(max(xi, 0), kIMG - 1), yc = min(max(yi, 0), kIMG - 1);
    float dv = depth[(size_t)b * (kIMG * kIMG) + yc * kIMG + xc];
    v = valid ? dv : 0.0f;
  }

  // count of samples <= THR (wave-uniform)
  unsigned long long mle = __ballot(lane < kR2 && v <= 1e-4f);
  int cnt = __popcll(mle);

  // bitonic sort ascending across 64 lanes (values finite or +inf, no NaN)
#pragma unroll
  for (int k = 2; k <= 64; k <<= 1) {
#pragma unroll
    for (int j = k >> 1; j > 0; j >>= 1) {
      float w = __shfl_xor(v, j, 64);
      bool up = ((lane & k) == 0);
      bool lower = ((lane & j) == 0);
      v = (up == lower) ? fminf(v, w) : fmaxf(v, w);
    }
  }

  int st = min(max(cnt, 1), kR2 - 1);
  int kk = (st + kR2 - 1) >> 1;        // med_ind in [24,48], wave-uniform
  float m = __shfl(v, kk, 64);
  if (lane == 0) med[wave] = m;
}

// K2: per-batch lower median of 68 medians; writes packed (median*500, mask).
__global__ __launch_bounds__(128) void k_mask(
    const float* __restrict__ med, float2* __restrict__ mf) {
  __shared__ float s[kL];
  __shared__ float mom_s;
  int b = blockIdx.x, t = threadIdx.x;
  if (t < kL) s[t] = med[b * kL + t];
  __syncthreads();
  if (t < kL) {
    float v = s[t];
    int rank = 0;
    for (int j = 0; j < kL; ++j) {
      float vj = s[j];
      rank += ((vj < v) || (vj == v && j < t)) ? 1 : 0;
    }
    if (rank == (kL - 1) / 2) mom_s = v;  // exactly one thread
  }
  __syncthreads();
  if (t < kL) {
    float v = s[t];
    float diff = fabsf(__fsub_rn(v, mom_s));
    float2 o;
    o.x = __fmul_rn(v, 500.0f);
    o.y = (diff < 0.18f) ? 1.0f : 0.0f;
    mf[b * kL + t] = o;
  }
}

// K3: 2 elements/thread over [512,68,68]; writes diff/mask + per-block
// masked smooth-L1 partials. NO fences/atomics (fence storm = R3 regression).
__global__ __launch_bounds__(256) void k_out(
    const float* __restrict__ rdp, const float2* __restrict__ mf,
    float* __restrict__ out_diff, float* __restrict__ out_mask,
    double* __restrict__ part) {
  __shared__ double sn[4], sd[4];
  int t = blockIdx.x * 256 + threadIdx.x;   // pair index
  int e = t * 2;
  unsigned b = (unsigned)e / (unsigned)kLL;
  int r = e - (int)b * kLL;
  unsigned i0 = (unsigned)r / (unsigned)kL;
  int j0 = r - (int)i0 * kL;
  unsigned i1 = (j0 == kL - 1) ? i0 + 1 : i0;
  int j1 = (j0 == kL - 1) ? 0 : j0 + 1;

  const float2* mfb = mf + b * kL;
  float2 a0 = mfb[i0], a1 = mfb[i1];
  float2 c0 = mfb[j0], c1 = mfb[j1];
  float2 rp = ((const float2*)rdp)[t];   // rdp base aligned, e even

  float diff0 = __fsub_rn(a0.x, c0.x);
  float diff1 = __fsub_rn(a1.x, c1.x);
  float mv0 = __fmul_rn(a0.y, c0.y);
  float mv1 = __fmul_rn(a1.y, c1.y);
  out_diff[e] = diff0; out_diff[e + 1] = diff1;
  out_mask[e] = mv0;   out_mask[e + 1] = mv1;

  float d0 = __fsub_rn(rp.x, diff0), d1 = __fsub_rn(rp.y, diff1);
  float ad0 = fabsf(d0), ad1 = fabsf(d1);
  float le0 = (ad0 < 1.0f) ? __fmul_rn(__fmul_rn(0.5f, d0), d0) : __fsub_rn(ad0, 0.5f);
  float le1 = (ad1 < 1.0f) ? __fmul_rn(__fmul_rn(0.5f, d1), d1) : __fsub_rn(ad1, 0.5f);
  double pn = (double)__fmul_rn(le0, mv0) + (double)__fmul_rn(le1, mv1);
  double pd = (double)mv0 + (double)mv1;

  for (int off = 32; off > 0; off >>= 1) {
    pn += __shfl_down(pn, off, 64);
    pd += __shfl_down(pd, off, 64);
  }
  int w = threadIdx.x >> 6;
  if ((threadIdx.x & 63) == 0) { sn[w] = pn; sd[w] = pd; }
  __syncthreads();
  if (threadIdx.x == 0) {
    part[2 * blockIdx.x + 0] = sn[0] + sn[1] + sn[2] + sn[3];
    part[2 * blockIdx.x + 1] = sd[0] + sd[1] + sd[2] + sd[3];
  }
}

__global__ __launch_bounds__(256) void k_final(
    const double* __restrict__ part, float* __restrict__ out0) {
  __shared__ double sn[4], sd[4];
  double pn = 0.0, pd = 0.0;
  for (int i = threadIdx.x; i < kOutBlocks; i += 256) {
    pn += part[2 * i + 0];
    pd += part[2 * i + 1];
  }
  for (int off = 32; off > 0; off >>= 1) {
    pn += __shfl_down(pn, off, 64);
    pd += __shfl_down(pd, off, 64);
  }
  int w = threadIdx.x >> 6;
  if ((threadIdx.x & 63) == 0) { sn[w] = pn; sd[w] = pd; }
  __syncthreads();
  if (threadIdx.x == 0) {
    double tn = sn[0] + sn[1] + sn[2] + sn[3];
    double td = sd[0] + sd[1] + sd[2] + sd[3];
    out0[0] = (float)(tn / (td + 1e-4));
  }
}

extern "C" void kernel_launch(void* const* d_in, const int* in_sizes, int n_in,
                              void* d_out, int out_size, void* d_ws, size_t ws_size,
                              hipStream_t stream) {
  const float* rdp   = (const float*)d_in[0];  // [512,68,68]
  const float* depth = (const float*)d_in[1];  // [512,1,224,224]
  const float* lmk   = (const float*)d_in[2];  // [512,68,2]
  const float* scale = (const float*)d_in[3];  // [512,2]
  const float* bbox  = (const float*)d_in[4];  // [512,4]

  float* out = (float*)d_out;
  float* out_diff = out + 1;
  float* out_mask = out + 1 + (size_t)kBS * kLL;

  char* ws = (char*)d_ws;
  float*  med  = (float*)(ws);                          // 139264 B
  float2* mf   = (float2*)(ws + 139264);                // 278528 B
  double* part = (double*)(ws + 139264 + 278528);       // 73984 B

  int nWaves = kBS * kL;          // 34816
  int nBlk1 = (nWaves + 3) / 4;   // 8704
  k_median<<<dim3(nBlk1), dim3(256), 0, stream>>>(depth, lmk, scale, bbox, med);
  k_mask<<<dim3(kBS), dim3(128), 0, stream>>>(med, mf);
  k_out<<<dim3(kOutBlocks), dim3(256), 0, stream>>>(rdp, mf, out_diff, out_mask, part);
  k_final<<<dim3(1), dim3(256), 0, stream>>>(part, out);
}

// Round 6
// 171.532 us; speedup vs baseline: 1.9492x; 1.0400x over previous
//
#include <hip/hip_runtime.h>
#include <cfloat>
#include <math.h>

static constexpr int kBS  = 512;
static constexpr int kL   = 68;
static constexpr int kIMG = 224;
static constexpr int kR2  = 49;
static constexpr int kLL  = kL * kL;                 // 4624
static constexpr int kChunks = 5;                    // 5*1024 >= 4624
static constexpr int kOutBlocks = kBS * kChunks;     // 2560

// jnp.linspace(-3.5,3.5,7)[k]/224*2 — JAX convex-combination linspace,
// exact op order, no contraction. k=6: step=1.0 -> exactly 3.5.
__device__ __forceinline__ float lin_off(int k) {
  float step = __fdiv_rn((float)k, 6.0f);
  float a = __fmul_rn(-3.5f, __fsub_rn(1.0f, step));
  float b = __fmul_rn(3.5f, step);
  float x = __fadd_rn(a, b);
  return __fmul_rn(__fdiv_rn(x, 224.0f), 2.0f);
}

// K1: one wave per (b,l) region; lanes 0..48 hold the 7x7 samples.
// Bitonic 64-lane sort + ballot count; selects k-th order statistic (R5-proven).
__global__ __launch_bounds__(256) void k_median(
    const float* __restrict__ depth, const float* __restrict__ lmk,
    const float* __restrict__ scale, const float* __restrict__ bbox,
    float* __restrict__ med) {
  int wave = blockIdx.x * 4 + (threadIdx.x >> 6);
  int lane = threadIdx.x & 63;
  if (wave >= kBS * kL) return;
  int b = wave / kL;

  float lmx = lmk[wave * 2 + 0];
  float lmy = lmk[wave * 2 + 1];
  float sx = scale[b * 2 + 0], sy = scale[b * 2 + 1];
  float bx = bbox[b * 4 + 0],  by = bbox[b * 4 + 1];

  float tx = __fsub_rn(lmx, bx);
  tx = __fmul_rn(tx, sx); tx = __fdiv_rn(tx, 224.0f); tx = __fmul_rn(tx, 2.0f);
  float flmx = __fsub_rn(tx, 1.0f);
  float ty = __fsub_rn(lmy, by);
  ty = __fmul_rn(ty, sy); ty = __fdiv_rn(ty, 224.0f); ty = __fmul_rn(ty, 2.0f);
  float flmy = __fsub_rn(ty, 1.0f);

  float v = INFINITY;  // pad lanes sort last; never selected
  if (lane < kR2) {
    int i = lane / 7, j = lane - i * 7;
    float gx = __fadd_rn(flmx, lin_off(j));
    float gy = __fadd_rn(flmy, lin_off(i));
    float ix = __fmul_rn(__fsub_rn(__fmul_rn(__fadd_rn(gx, 1.0f), 224.0f), 1.0f), 0.5f);
    float iy = __fmul_rn(__fsub_rn(__fmul_rn(__fadd_rn(gy, 1.0f), 224.0f), 1.0f), 0.5f);
    int xi = (int)rintf(ix), yi = (int)rintf(iy);
    bool valid = (xi >= 0) && (xi < kIMG) && (yi >= 0) && (yi < kIMG);
    int xc = min(max(xi, 0), kIMG - 1), yc = min(max(yi, 0), kIMG - 1);
    float dv = depth[(size_t)b * (kIMG * kIMG) + yc * kIMG + xc];
    v = valid ? dv : 0.0f;
  }

  unsigned long long mle = __ballot(lane < kR2 && v <= 1e-4f);
  int cnt = __popcll(mle);

#pragma unroll
  for (int k = 2; k <= 64; k <<= 1) {
#pragma unroll
    for (int j = k >> 1; j > 0; j >>= 1) {
      float w = __shfl_xor(v, j, 64);
      bool up = ((lane & k) == 0);
      bool lower = ((lane & j) == 0);
      v = (up == lower) ? fminf(v, w) : fmaxf(v, w);
    }
  }

  int st = min(max(cnt, 1), kR2 - 1);
  int kk = (st + kR2 - 1) >> 1;        // med_ind in [24,48], wave-uniform
  float m = __shfl(v, kk, 64);
  if (lane == 0) med[wave] = m;
}

// K2: fused mask + outputs. Grid (chunk, batch); each block recomputes the
// batch's median-of-medians in LDS (identical fp compare sequence to the old
// k_mask), then 4 elems/thread: diff/mask writes + masked smooth-L1 partials.
// NO fences/atomics (fence storm = R3 regression).
__global__ __launch_bounds__(256) void k_out(
    const float* __restrict__ rdp, const float* __restrict__ med,
    float* __restrict__ out_diff, float* __restrict__ out_mask,
    double* __restrict__ part) {
  __shared__ float s_med[kL], s_m[kL], s_f[kL];
  __shared__ float mom_s;
  __shared__ double sn[4], sd[4];
  int b = blockIdx.y, chunk = blockIdx.x, t = threadIdx.x;

  if (t < kL) s_med[t] = med[b * kL + t];
  __syncthreads();
  if (t < kL) {
    float v = s_med[t];
    int rank = 0;
    for (int j = 0; j < kL; ++j) {
      float vj = s_med[j];
      rank += ((vj < v) || (vj == v && j < t)) ? 1 : 0;
    }
    if (rank == (kL - 1) / 2) mom_s = v;  // lower median, exactly one thread
  }
  __syncthreads();
  if (t < kL) {
    float v = s_med[t];
    s_m[t] = __fmul_rn(v, 500.0f);
    s_f[t] = (fabsf(__fsub_rn(v, mom_s)) < 0.18f) ? 1.0f : 0.0f;
  }
  __syncthreads();

  int e = chunk * 1024 + t * 4;        // e % 4 == 0
  double pn = 0.0, pd = 0.0;
  if (e < kLL) {
    unsigned i = (unsigned)e / (unsigned)kL;
    int j = e - (int)i * kL;           // j % 4 == 0, j <= 64: no wrap in 4 elems
    size_t base = (size_t)b * kLL + e; // 4624 % 16 == 0 -> 16B-aligned
    float4 rp = *(const float4*)(rdp + base);
    float mi = s_m[i], fi = s_f[i];
    float rq[4] = {rp.x, rp.y, rp.z, rp.w};
#pragma unroll
    for (int q = 0; q < 4; ++q) {
      float mj = s_m[j + q], fj = s_f[j + q];
      float diff = __fsub_rn(mi, mj);
      float mv = __fmul_rn(fi, fj);
      out_diff[base + q] = diff;
      out_mask[base + q] = mv;
      float d = __fsub_rn(rq[q], diff);
      float ad = fabsf(d);
      float le = (ad < 1.0f) ? __fmul_rn(__fmul_rn(0.5f, d), d)
                             : __fsub_rn(ad, 0.5f);
      pn += (double)__fmul_rn(le, mv);
      pd += (double)mv;
    }
  }

  for (int off = 32; off > 0; off >>= 1) {
    pn += __shfl_down(pn, off, 64);
    pd += __shfl_down(pd, off, 64);
  }
  int w = t >> 6;
  if ((t & 63) == 0) { sn[w] = pn; sd[w] = pd; }
  __syncthreads();
  if (t == 0) {
    int blkid = b * kChunks + chunk;   // 0..2559
    part[2 * blkid + 0] = sn[0] + sn[1] + sn[2] + sn[3];
    part[2 * blkid + 1] = sd[0] + sd[1] + sd[2] + sd[3];
  }
}

__global__ __launch_bounds__(256) void k_final(
    const double* __restrict__ part, float* __restrict__ out0) {
  __shared__ double sn[4], sd[4];
  double pn = 0.0, pd = 0.0;
  for (int i = threadIdx.x; i < kOutBlocks; i += 256) {
    pn += part[2 * i + 0];
    pd += part[2 * i + 1];
  }
  for (int off = 32; off > 0; off >>= 1) {
    pn += __shfl_down(pn, off, 64);
    pd += __shfl_down(pd, off, 64);
  }
  int w = threadIdx.x >> 6;
  if ((threadIdx.x & 63) == 0) { sn[w] = pn; sd[w] = pd; }
  __syncthreads();
  if (threadIdx.x == 0) {
    double tn = sn[0] + sn[1] + sn[2] + sn[3];
    double td = sd[0] + sd[1] + sd[2] + sd[3];
    out0[0] = (float)(tn / (td + 1e-4));
  }
}

extern "C" void kernel_launch(void* const* d_in, const int* in_sizes, int n_in,
                              void* d_out, int out_size, void* d_ws, size_t ws_size,
                              hipStream_t stream) {
  const float* rdp   = (const float*)d_in[0];  // [512,68,68]
  const float* depth = (const float*)d_in[1];  // [512,1,224,224]
  const float* lmk   = (const float*)d_in[2];  // [512,68,2]
  const float* scale = (const float*)d_in[3];  // [512,2]
  const float* bbox  = (const float*)d_in[4];  // [512,4]

  float* out = (float*)d_out;
  float* out_diff = out + 1;
  float* out_mask = out + 1 + (size_t)kBS * kLL;

  char* ws = (char*)d_ws;
  float*  med  = (float*)(ws);                  // 139264 B
  double* part = (double*)(ws + 139264);        // 40960 B

  int nWaves = kBS * kL;          // 34816
  int nBlk1 = (nWaves + 3) / 4;   // 8704
  k_median<<<dim3(nBlk1), dim3(256), 0, stream>>>(depth, lmk, scale, bbox, med);
  k_out<<<dim3(kChunks, kBS), dim3(256), 0, stream>>>(rdp, med, out_diff, out_mask, part);
  k_final<<<dim3(1), dim3(256), 0, stream>>>(part, out);
}